// Round 17
// baseline (78.149 us; speedup 1.0000x reference)
//
#include <hip/hip_runtime.h>
#include <hip/hip_bf16.h>

#define DEV __device__ __forceinline__

typedef unsigned short u16;
typedef __attribute__((ext_vector_type(8))) short short8;   // 8 bf16 (4 VGPRs)
typedef __attribute__((ext_vector_type(4))) float f32x4;    // 16x16 MFMA C/D
typedef __attribute__((ext_vector_type(16))) float f32x16;  // 32x32 MFMA C/D

// ---------- helpers ----------
DEV u16 f2bf(float f) {               // RNE float -> bf16 bits
  union { float f; unsigned u; } v; v.f = f;
  unsigned r = v.u + 0x7FFFu + ((v.u >> 16) & 1u);
  return (u16)(r >> 16);
}

DEV float bf2f(u16 b) {
  union { unsigned u; float f; } v; v.u = ((unsigned)b) << 16; return v.f;
}

DEV unsigned cvtpk(float lo, float hi) {  // packed bf16x2 (RNE)
  unsigned r;
  asm("v_cvt_pk_bf16_f32 %0, %1, %2" : "=v"(r) : "v"(lo), "v"(hi));
  return r;
}

DEV void async_ld16(const u16* g, u16* l) {
  __builtin_amdgcn_global_load_lds((__attribute__((address_space(1))) void*)g,
                                   (__attribute__((address_space(3))) void*)l,
                                   16, 0, 0);
}

DEV f32x4 mfma16(short8 a, short8 b, f32x4 c) {
  return __builtin_amdgcn_mfma_f32_16x16x32_bf16(a, b, c, 0, 0, 0);
}
DEV f32x16 mfma32(short8 a, short8 b, f32x16 c) {
  return __builtin_amdgcn_mfma_f32_32x32x16_bf16(a, b, c, 0, 0, 0);
}

DEV short8 mkfrag(unsigned w0, unsigned w1, unsigned w2, unsigned w3) {
  union { unsigned u[4]; short8 s; } u;
  u.u[0] = w0; u.u[1] = w1; u.u[2] = w2; u.u[3] = w3;
  return u.s;
}

// swizzled LDS b128 read from a [rows][64] bf16 tile (128B rows, st-style XOR)
DEV short8 lds_rd(const u16* buf, int row, int colb) {
  return *(const short8*)((const char*)buf + row*128 + (colb ^ ((row & 7) << 4)));
}

#define QSCALE (0.125f * 1.4426950408889634f)

// ---------- kernel 1: fused prep (x->bf16 | W1 | Weff) ----------
__global__ __launch_bounds__(256) void k_prep(const float* __restrict__ x,
    const float* __restrict__ wq, const float* __restrict__ wk,
    const float* __restrict__ wv, const float* __restrict__ wqa,
    const float* __restrict__ wka, const float* __restrict__ wva,
    const float* __restrict__ wo, const float* __restrict__ wos,
    u16* __restrict__ xb, u16* __restrict__ W1, u16* __restrict__ Weff) {
  const int bid = blockIdx.x;
  if (bid < 1024) {                     // x fp32 -> bf16 (1048576 float4)
    int i = bid*256 + threadIdx.x;
    for (; i < 1048576; i += 1024*256) {
      float4 v = ((const float4*)x)[i];
      ushort4 o;
      o.x = f2bf(v.x); o.y = f2bf(v.y); o.z = f2bf(v.z); o.w = f2bf(v.w);
      ((ushort4*)xb)[i] = o;
    }
  } else if (bid < 1280) {              // W1 row
    const int row = bid - 1024;
    const float* src = nullptr; float sc = 1.f;
    if (row < 64)       { src = wq  + row*2048;       sc = QSCALE; }
    else if (row < 128) { src = wk  + (row-64)*2048;  }
    else if (row < 192) { src = wv  + (row-128)*2048; }
    else if (row < 200) { src = wqa + (row-192)*2048; sc = 2.f*QSCALE; }
    else if (row < 208) { src = wka + (row-200)*2048; sc = 2.f; }
    else if (row < 216) { src = wva + (row-208)*2048; sc = 2.f; }
    for (int c = threadIdx.x; c < 2048; c += 256)
      W1[row*2048 + c] = src ? f2bf(src[c]*sc) : (u16)0;
  } else {                              // Weff row
    const int e = bid - 1280;
    for (int f = threadIdx.x; f < 1024; f += 256)
      Weff[e*1024 + f] = f2bf(wos[e*1024 + f] + wo[e*64 + (f & 63)]);
  }
}

// ---------- GEMM: C = A*B^T, BK=64, swizzled LDS, XCD-aware tile swizzle ----
// OBF16: write bf16 C (split-K partials) instead of fp32.
template<int BM, int BN, bool OBF16>
__global__ __launch_bounds__(512)
void k_gemm_bt(const u16* __restrict__ A, const u16* __restrict__ B,
               void* __restrict__ Cv, int M, int N, int K, int kslice) {
  constexpr int NWC = (BN >= 128) ? 4 : 2;      // wave grid cols
  constexpr int NWR = 8 / NWC;                  // wave grid rows
  constexpr int WM = BM / NWR, WN = BN / NWC;
  constexpr int FM = WM/16, FN = WN/16;
  __shared__ u16 As[BM*64];                     // [row][64], 128B rows, swizzled
  __shared__ u16 Bs[BN*64];
  const int tid = threadIdx.x;
  const int w = tid >> 6, l = tid & 63;
  const int wm = (w / NWC)*WM, wn = (w % NWC)*WN;

  // T1: bijective XCD swizzle (requires total blocks % 8 == 0 — true for our
  // 512-block grids). Blocks resident on one XCD (bid%8 under round-robin)
  // process CONSECUTIVE linear tiles -> A-panel reuse hits the same L2.
  const int gx = gridDim.x, gy = gridDim.y;
  const int tot = gx*gy*gridDim.z;
  int lin = blockIdx.x + gx*(blockIdx.y + gy*blockIdx.z);
  if ((tot & 7) == 0) lin = (lin & 7)*(tot >> 3) + (lin >> 3);
  const int bx = lin % gx;
  const int t2 = lin / gx;
  const int by = t2 % gy, bz = t2 / gy;

  const int tm = by*BM, tn = bx*BN;
  const int k0 = bz * kslice;
  const int sr = (w << 3) + (l >> 3);           // staging row (per 64-row call)
  const int sc = (((l & 7) ^ (l >> 3)) << 3);   // inverse-swizzled src col (u16)
  const int la = l & 15, lg = l >> 4;

  f32x4 acc[FM][FN];
#pragma unroll
  for (int i = 0; i < FM; ++i)
#pragma unroll
    for (int j = 0; j < FN; ++j) acc[i][j] = (f32x4){0.f,0.f,0.f,0.f};

  const int nk = kslice >> 6;
  for (int kt = 0; kt < nk; ++kt) {
    const int kk = k0 + (kt << 6);
#pragma unroll
    for (int j = 0; j < BM/64; ++j)
      async_ld16(A + (size_t)(tm + j*64 + sr)*K + kk + sc, &As[(j*64 + w*8)*64]);
#pragma unroll
    for (int j = 0; j < BN/64; ++j)
      async_ld16(B + (size_t)(tn + j*64 + sr)*K + kk + sc, &Bs[(j*64 + w*8)*64]);
    __syncthreads();
    short8 af[FM][2], bfr[FN][2];
#pragma unroll
    for (int mi = 0; mi < FM; ++mi)
#pragma unroll
      for (int ks = 0; ks < 2; ++ks)
        af[mi][ks] = lds_rd(As, wm + mi*16 + la, ks*64 + lg*16);
#pragma unroll
    for (int ni = 0; ni < FN; ++ni)
#pragma unroll
      for (int ks = 0; ks < 2; ++ks)
        bfr[ni][ks] = lds_rd(Bs, wn + ni*16 + la, ks*64 + lg*16);
#pragma unroll
    for (int ks = 0; ks < 2; ++ks)
#pragma unroll
      for (int mi = 0; mi < FM; ++mi)
#pragma unroll
        for (int ni = 0; ni < FN; ++ni)
          acc[mi][ni] = mfma16(af[mi][ks], bfr[ni][ks], acc[mi][ni]);
    __syncthreads();
  }
#pragma unroll
  for (int mi = 0; mi < FM; ++mi)
#pragma unroll
    for (int ni = 0; ni < FN; ++ni) {
      const int r0 = tm + wm + mi*16 + lg*4;
      const int cc = tn + wn + ni*16 + la;
      if constexpr (OBF16) {
        u16* C = (u16*)Cv + (size_t)bz * M * N;
#pragma unroll
        for (int r = 0; r < 4; ++r)
          C[(size_t)(r0 + r)*N + cc] = f2bf(acc[mi][ni][r]);
      } else {
        float* C = (float*)Cv + (size_t)bz * M * N;
#pragma unroll
        for (int r = 0; r < 4; ++r)
          C[(size_t)(r0 + r)*N + cc] = acc[mi][ni][r];
      }
    }
}

// ---------- kernel: expand base+LoRA, RoPE, write Q/K/V (bf16 partials) ----------
__global__ __launch_bounds__(256)
void k_expand(const u16* __restrict__ proj, const float* __restrict__ wqb,
              const float* __restrict__ wkb, const float* __restrict__ wvb,
              const float* __restrict__ freq, u16* __restrict__ Q,
              u16* __restrict__ Kb, u16* __restrict__ Vt) {
  __shared__ float prs[256];
  const int s = blockIdx.x;
  {
    const int c = threadIdx.x;
    const u16* p0 = proj + s*256;
    float acc = 0.f;
#pragma unroll
    for (int k = 0; k < 8; ++k) acc += bf2f(p0[c + k*524288]);
    prs[c] = acc;
  }
  __syncthreads();
  const int d = threadIdx.x & 63;
  const int w = threadIdx.x >> 6;
  const float cs = freq[s*64 + (d & 62)];
  const float sn = freq[s*64 + (d & 62) + 1];
#pragma unroll
  for (int pass = 0; pass < 6; ++pass) {
    const int slot = pass*4 + w;
    int bcol, tb; const float* wb;
    if (slot < 16)      { bcol = 0;   tb = 192; wb = wqb + (slot*64 + d)*8; }
    else if (slot < 20) { bcol = 64;  tb = 200; wb = wkb + ((slot-16)*64 + d)*8; }
    else                { bcol = 128; tb = 208; wb = wvb + ((slot-20)*64 + d)*8; }
    float val = prs[bcol + d];
#pragma unroll
    for (int r = 0; r < 8; ++r) val += prs[tb + r] * wb[r];
    if (slot < 20) {  // RoPE
      float partner = __shfl_xor(val, 1);
      val = (d & 1) ? (partner*sn + val*cs) : (val*cs - partner*sn);
    }
    u16 o = f2bf(val);
    if (slot < 16)      Q [((size_t)slot*2048 + s)*64 + d] = o;
    else if (slot < 20) Kb[((size_t)(slot-16)*2048 + s)*64 + d] = o;
    else                Vt[(size_t)(slot-20)*131072 + (size_t)d*2048 + s] = o;
  }
}

// ---------- kernel: causal flash attention (v14: v10 + counted vmcnt) ----------
__global__ __launch_bounds__(256, 4)
void k_attn(const u16* __restrict__ Q, const u16* __restrict__ Kb,
            const u16* __restrict__ Vt, u16* __restrict__ O) {
  __shared__ __align__(16) char smem[33792];  // 4x8KB wave staging | comb | scr
  const int w = threadIdx.x >> 6, l = threadIdx.x & 63;
  const int bid = blockIdx.x;
  const int h = bid & 15, kh = h >> 2;
  const int z = bid >> 4;
  const int a = z & 15, b = z >> 4;            // stride-256 co-residents share a
  const int qs = (b << 4) | ((b & 1) ? (15 - a) : a);  // per-CU work pairing
  const int q0 = qs*32;
  const int lq = l & 31, hh = l >> 5;
  const int qg = q0 + lq;

  u16* kbuf = (u16*)(smem + w*8192);           // [32 t][64 d]  4KB, swizzled
  u16* vbuf = (u16*)(smem + w*8192 + 4096);    // [32 r][d=r|r+32][32 t] 4KB

  const u16* Qh = Q  + (size_t)h *131072;
  const u16* Kh = Kb + (size_t)kh*131072;
  const u16* Vh = Vt + (size_t)kh*131072;

  short8 bq[4];
#pragma unroll
  for (int ks = 0; ks < 4; ++ks)
    bq[ks] = *(const short8*)&Qh[qg*64 + ks*16 + hh*8];

  f32x16 acc0, acc1;                // O^T [d][q] partial (d 0..31 / 32..63)
#pragma unroll
  for (int r = 0; r < 16; ++r) { acc0[r] = 0.f; acc1[r] = 0.f; }
  float lsum = 0.f;
  const float SM = 20.f;            // static softmax offset (log2 domain)

  const int nt = qs + 1;            // 32-row t-tiles

#define STAGE_K(T0)                                                       \
  {                                                                       \
    const int t0_ = (T0);                                                 \
    _Pragma("unroll")                                                     \
    for (int j = 0; j < 4; ++j) {                                         \
      const int c = j*64 + l;                                             \
      const int row = c >> 3, e = (c & 7) ^ (row & 7);                    \
      async_ld16(Kh + (size_t)(t0_ + row)*64 + e*8, kbuf + j*512);        \
    }                                                                     \
  }
#define STAGE_V(T0)                                                       \
  {                                                                       \
    const int t0_ = (T0);                                                 \
    _Pragma("unroll")                                                     \
    for (int j = 0; j < 4; ++j) {                                         \
      const int c = j*64 + l;                                             \
      const int row = c >> 3, e = (c & 7) ^ (row & 7);                    \
      const int dd = row + (e >> 2)*32;                                   \
      async_ld16(Vh + (size_t)dd*2048 + t0_ + (e & 3)*8, vbuf + j*512);   \
    }                                                                     \
  }

  if (w < nt) { STAGE_K(w*32); STAGE_V(w*32); }

  for (int tt = w; tt < nt; tt += 4) {
    // outstanding here: K(tt) x4 (oldest), V(tt) x4 -> wait K only
    asm volatile("s_waitcnt vmcnt(4)" ::: "memory");
    __builtin_amdgcn_sched_barrier(0);
    // ---- K frags -> regs; fence; restage K (overlaps QK^T) ----
    short8 ak[4];
#pragma unroll
    for (int ks = 0; ks < 4; ++ks)
      ak[ks] = lds_rd(kbuf, lq, ks*32 + hh*16);
    asm volatile("s_waitcnt lgkmcnt(0)" ::: "memory");
    __builtin_amdgcn_sched_barrier(0);
    const bool restage = (tt + 4 < nt);
    if (restage) STAGE_K((tt + 4)*32);

    // ---- QK^T swapped: S^T[t32][q32] = mfma(K rows, Q rows) ----
    f32x16 s;
#pragma unroll
    for (int r = 0; r < 16; ++r) s[r] = 0.f;
    __builtin_amdgcn_s_setprio(1);
#pragma unroll
    for (int ks = 0; ks < 4; ++ks)
      s = mfma32(ak[ks], bq[ks], s);
    __builtin_amdgcn_s_setprio(0);

    // ---- causal mask (last tile only) ----
    const int t0 = tt*32;
    if (t0 + 31 > q0) {
#pragma unroll
      for (int r = 0; r < 16; ++r) {
        const int tl = (r & 3) + ((r >> 2) << 3) + (hh << 2);
        if (t0 + tl > qg) s[r] = -1e30f;
      }
    }

    // ---- wait V(tt) (oldest remaining); K(tt+4) stays in flight ----
    if (restage) { asm volatile("s_waitcnt vmcnt(4)" ::: "memory"); }
    else         { asm volatile("s_waitcnt vmcnt(0)" ::: "memory"); }
    __builtin_amdgcn_sched_barrier(0);
    short8 av[2][2];
#pragma unroll
    for (int dh = 0; dh < 2; ++dh)
#pragma unroll
      for (int k2 = 0; k2 < 2; ++k2)
        av[dh][k2] = lds_rd(vbuf, lq, (dh*4 + k2*2 + hh)*16);

    // ---- P = exp2(S - SM), packed bf16x2 ----
    unsigned cw[4][2];
    float psum = 0.f;
#pragma unroll
    for (int rq = 0; rq < 4; ++rq) {
      float a0 = exp2f(s[4*rq+0] - SM), a1 = exp2f(s[4*rq+1] - SM);
      float a2 = exp2f(s[4*rq+2] - SM), a3 = exp2f(s[4*rq+3] - SM);
      psum += (a0 + a1) + (a2 + a3);
      cw[rq][0] = cvtpk(a0, a1); cw[rq][1] = cvtpk(a2, a3);
    }
    lsum += psum;

    // ---- fence V reads; restage V (overlaps exchange + PV) ----
    asm volatile("s_waitcnt lgkmcnt(0)" ::: "memory");
    __builtin_amdgcn_sched_barrier(0);
    if (restage) STAGE_V((tt + 4)*32);

    // ---- cross-half exchange -> PV B-fragments ----
    unsigned y00 = __shfl_xor(hh ? cw[0][0] : cw[1][0], 32);
    unsigned y01 = __shfl_xor(hh ? cw[0][1] : cw[1][1], 32);
    unsigned y10 = __shfl_xor(hh ? cw[2][0] : cw[3][0], 32);
    unsigned y11 = __shfl_xor(hh ? cw[2][1] : cw[3][1], 32);
    short8 p0 = hh ? mkfrag(y00, y01, cw[1][0], cw[1][1])
                   : mkfrag(cw[0][0], cw[0][1], y00, y01);
    short8 p1 = hh ? mkfrag(y10, y11, cw[3][0], cw[3][1])
                   : mkfrag(cw[2][0], cw[2][1], y10, y11);

    // ---- PV: O^T[d][q] += mfma(V^T rows (k=t), P rows (k=t)) ----
    __builtin_amdgcn_s_setprio(1);
    acc0 = mfma32(av[0][0], p0, acc0);
    acc1 = mfma32(av[1][0], p0, acc1);
    acc0 = mfma32(av[0][1], p1, acc0);
    acc1 = mfma32(av[1][1], p1, acc1);
    __builtin_amdgcn_s_setprio(0);
  }
#undef STAGE_K
#undef STAGE_V

  // ---- combine: waves 1-3 publish partials; wave 0 sums + epilogue ----
  __syncthreads();                      // staging LDS now dead -> reuse
  float* comb = (float*)smem;           // [3][64][33] f32 = 25.3KB
  u16* scr = (u16*)(smem + 26624);      // 4KB transpose scratch
  if (w > 0) {
    float* cb = comb + ((w-1)*64 + l)*33;
#pragma unroll
    for (int r = 0; r < 16; ++r) { cb[r] = acc0[r]; cb[16+r] = acc1[r]; }
    cb[32] = lsum;
  }
  __syncthreads();
  if (w == 0) {
#pragma unroll
    for (int j = 0; j < 3; ++j) {
      const float* cb = comb + (j*64 + l)*33;
#pragma unroll
      for (int r = 0; r < 16; ++r) { acc0[r] += cb[r]; acc1[r] += cb[16+r]; }
      lsum += cb[32];
    }
    lsum += __shfl_xor(lsum, 32);
    const float inv = 1.f / lsum;
#pragma unroll
    for (int dt = 0; dt < 2; ++dt)
#pragma unroll
      for (int rq = 0; rq < 4; ++rq) {
        float v0 = (dt ? acc1[4*rq+0] : acc0[4*rq+0]) * inv;
        float v1 = (dt ? acc1[4*rq+1] : acc0[4*rq+1]) * inv;
        float v2 = (dt ? acc1[4*rq+2] : acc0[4*rq+2]) * inv;
        float v3 = (dt ? acc1[4*rq+3] : acc0[4*rq+3]) * inv;
        const int dby = dt*64 + rq*16 + hh*8;
        const int by = lq*128 + (dby ^ ((lq & 7) << 4));
        *(unsigned*)((char*)scr + by)     = cvtpk(v0, v1);
        *(unsigned*)((char*)scr + by + 4) = cvtpk(v2, v3);
      }
#pragma unroll
    for (int qq = 0; qq < 4; ++qq) {
      const int qrow = qq*8 + (l >> 3);
      const int by = qrow*128 + (((l & 7) << 4) ^ ((qrow & 7) << 4));
      short8 v = *(const short8*)((const char*)scr + by);
      *(short8*)&O[(size_t)(q0 + qrow)*1024 + h*64 + (l & 7)*8] = v;
    }
  }
}

// ---------- launch ----------
extern "C" void kernel_launch(void* const* d_in, const int* in_sizes, int n_in,
                              void* d_out, int out_size, void* d_ws, size_t ws_size,
                              hipStream_t stream) {
  const float* x    = (const float*)d_in[0];
  const float* freq = (const float*)d_in[1];
  const float* wq   = (const float*)d_in[2];
  const float* wqa  = (const float*)d_in[3];
  const float* wqb  = (const float*)d_in[4];
  const float* wk   = (const float*)d_in[5];
  const float* wka  = (const float*)d_in[6];
  const float* wkb  = (const float*)d_in[7];
  const float* wv   = (const float*)d_in[8];
  const float* wva  = (const float*)d_in[9];
  const float* wvb  = (const float*)d_in[10];
  const float* wo   = (const float*)d_in[11];
  const float* wos  = (const float*)d_in[12];

  char* ws = (char*)d_ws;
  u16*  x_bf = (u16*)ws;
  u16*  Qb   = (u16*)ws;                  // reuses x_bf region (stream-ordered)
  u16*  Kbuf = (u16*)(ws + (4u<<20));
  u16*  Vtb  = (u16*)(ws + (5u<<20));
  u16*  W1   = (u16*)(ws + (8u<<20));
  u16*  Weff = (u16*)(ws + (9u<<20));
  u16*  proj = (u16*)(ws + (13u<<20));    // 8 x [2048][256] bf16 = 8MB
  u16*  Obf  = (u16*)(ws + (13u<<20));    // reuses proj region (after expand)

  k_prep    <<<3328, 256, 0, stream>>>(x, wq, wk, wv, wqa, wka, wva, wo, wos,
                                       x_bf, W1, Weff);
  k_gemm_bt<128,64,true><<<dim3(4,16,8), 512, 0, stream>>>(x_bf, W1, proj,
                                                           2048, 256, 2048, 256);
  k_expand  <<<dim3(2048), 256, 0, stream>>>(proj, wqb, wkb, wvb, freq, Qb, Kbuf, Vtb);
  k_attn    <<<dim3(1024), 256, 0, stream>>>(Qb, Kbuf, Vtb, Obf);
  k_gemm_bt<64,128,false><<<dim3(16,32,1), 512, 0, stream>>>(Obf, Weff, (float*)d_out,
                                                             2048, 2048, 1024, 1024);
}

// Round 20
// 77.219 us; speedup vs baseline: 1.0120x; 1.0120x over previous
//
#include <hip/hip_runtime.h>
#include <hip/hip_bf16.h>

#define DEV __device__ __forceinline__

typedef unsigned short u16;
typedef __attribute__((ext_vector_type(8))) short short8;   // 8 bf16 (4 VGPRs)
typedef __attribute__((ext_vector_type(4))) float f32x4;    // 16x16 MFMA C/D
typedef __attribute__((ext_vector_type(16))) float f32x16;  // 32x32 MFMA C/D

// ---------- helpers ----------
DEV u16 f2bf(float f) {               // RNE float -> bf16 bits
  union { float f; unsigned u; } v; v.f = f;
  unsigned r = v.u + 0x7FFFu + ((v.u >> 16) & 1u);
  return (u16)(r >> 16);
}

DEV float bf2f(u16 b) {
  union { unsigned u; float f; } v; v.u = ((unsigned)b) << 16; return v.f;
}

DEV unsigned cvtpk(float lo, float hi) {  // packed bf16x2 (RNE)
  unsigned r;
  asm("v_cvt_pk_bf16_f32 %0, %1, %2" : "=v"(r) : "v"(lo), "v"(hi));
  return r;
}

DEV void async_ld16(const u16* g, u16* l) {
  __builtin_amdgcn_global_load_lds((__attribute__((address_space(1))) void*)g,
                                   (__attribute__((address_space(3))) void*)l,
                                   16, 0, 0);
}

DEV f32x4 mfma16(short8 a, short8 b, f32x4 c) {
  return __builtin_amdgcn_mfma_f32_16x16x32_bf16(a, b, c, 0, 0, 0);
}
DEV f32x16 mfma32(short8 a, short8 b, f32x16 c) {
  return __builtin_amdgcn_mfma_f32_32x32x16_bf16(a, b, c, 0, 0, 0);
}

DEV short8 mkfrag(unsigned w0, unsigned w1, unsigned w2, unsigned w3) {
  union { unsigned u[4]; short8 s; } u;
  u.u[0] = w0; u.u[1] = w1; u.u[2] = w2; u.u[3] = w3;
  return u.s;
}

// swizzled LDS b128 read from a [rows][64] bf16 tile (128B rows, st-style XOR)
DEV short8 lds_rd(const u16* buf, int row, int colb) {
  return *(const short8*)((const char*)buf + row*128 + (colb ^ ((row & 7) << 4)));
}

#define QSCALE (0.125f * 1.4426950408889634f)

// ---------- kernel 1: fused prep (x->bf16 | W1 | Weff) ----------
__global__ __launch_bounds__(256) void k_prep(const float* __restrict__ x,
    const float* __restrict__ wq, const float* __restrict__ wk,
    const float* __restrict__ wv, const float* __restrict__ wqa,
    const float* __restrict__ wka, const float* __restrict__ wva,
    const float* __restrict__ wo, const float* __restrict__ wos,
    u16* __restrict__ xb, u16* __restrict__ W1, u16* __restrict__ Weff) {
  const int bid = blockIdx.x;
  if (bid < 1024) {                     // x fp32 -> bf16 (1048576 float4)
    int i = bid*256 + threadIdx.x;
    for (; i < 1048576; i += 1024*256) {
      float4 v = ((const float4*)x)[i];
      ushort4 o;
      o.x = f2bf(v.x); o.y = f2bf(v.y); o.z = f2bf(v.z); o.w = f2bf(v.w);
      ((ushort4*)xb)[i] = o;
    }
  } else if (bid < 1280) {              // W1 row
    const int row = bid - 1024;
    const float* src = nullptr; float sc = 1.f;
    if (row < 64)       { src = wq  + row*2048;       sc = QSCALE; }
    else if (row < 128) { src = wk  + (row-64)*2048;  }
    else if (row < 192) { src = wv  + (row-128)*2048; }
    else if (row < 200) { src = wqa + (row-192)*2048; sc = 2.f*QSCALE; }
    else if (row < 208) { src = wka + (row-200)*2048; sc = 2.f; }
    else if (row < 216) { src = wva + (row-208)*2048; sc = 2.f; }
    for (int c = threadIdx.x; c < 2048; c += 256)
      W1[row*2048 + c] = src ? f2bf(src[c]*sc) : (u16)0;
  } else {                              // Weff row
    const int e = bid - 1280;
    for (int f = threadIdx.x; f < 1024; f += 256)
      Weff[e*1024 + f] = f2bf(wos[e*1024 + f] + wo[e*64 + (f & 63)]);
  }
}

// ---------- GEMM (r14 version): C = A*B^T, BK=64, swizzled LDS ----------
template<int BM, int BN, bool OBF16>
__global__ __launch_bounds__(512)
void k_gemm_bt(const u16* __restrict__ A, const u16* __restrict__ B,
               void* __restrict__ Cv, int M, int N, int K, int kslice) {
  constexpr int NWC = (BN >= 128) ? 4 : 2;      // wave grid cols
  constexpr int NWR = 8 / NWC;                  // wave grid rows
  constexpr int WM = BM / NWR, WN = BN / NWC;
  constexpr int FM = WM/16, FN = WN/16;
  __shared__ u16 As[BM*64];                     // [row][64], 128B rows, swizzled
  __shared__ u16 Bs[BN*64];
  const int tid = threadIdx.x;
  const int w = tid >> 6, l = tid & 63;
  const int wm = (w / NWC)*WM, wn = (w % NWC)*WN;
  const int tm = blockIdx.y*BM, tn = blockIdx.x*BN;
  const int k0 = blockIdx.z * kslice;
  const int sr = (w << 3) + (l >> 3);           // staging row (per 64-row call)
  const int sc = (((l & 7) ^ (l >> 3)) << 3);   // inverse-swizzled src col (u16)
  const int la = l & 15, lg = l >> 4;

  f32x4 acc[FM][FN];
#pragma unroll
  for (int i = 0; i < FM; ++i)
#pragma unroll
    for (int j = 0; j < FN; ++j) acc[i][j] = (f32x4){0.f,0.f,0.f,0.f};

  const int nk = kslice >> 6;
  for (int kt = 0; kt < nk; ++kt) {
    const int kk = k0 + (kt << 6);
#pragma unroll
    for (int j = 0; j < BM/64; ++j)
      async_ld16(A + (size_t)(tm + j*64 + sr)*K + kk + sc, &As[(j*64 + w*8)*64]);
#pragma unroll
    for (int j = 0; j < BN/64; ++j)
      async_ld16(B + (size_t)(tn + j*64 + sr)*K + kk + sc, &Bs[(j*64 + w*8)*64]);
    __syncthreads();
    short8 af[FM][2], bfr[FN][2];
#pragma unroll
    for (int mi = 0; mi < FM; ++mi)
#pragma unroll
      for (int ks = 0; ks < 2; ++ks)
        af[mi][ks] = lds_rd(As, wm + mi*16 + la, ks*64 + lg*16);
#pragma unroll
    for (int ni = 0; ni < FN; ++ni)
#pragma unroll
      for (int ks = 0; ks < 2; ++ks)
        bfr[ni][ks] = lds_rd(Bs, wn + ni*16 + la, ks*64 + lg*16);
#pragma unroll
    for (int ks = 0; ks < 2; ++ks)
#pragma unroll
      for (int mi = 0; mi < FM; ++mi)
#pragma unroll
        for (int ni = 0; ni < FN; ++ni)
          acc[mi][ni] = mfma16(af[mi][ks], bfr[ni][ks], acc[mi][ni]);
    __syncthreads();
  }
#pragma unroll
  for (int mi = 0; mi < FM; ++mi)
#pragma unroll
    for (int ni = 0; ni < FN; ++ni) {
      const int r0 = tm + wm + mi*16 + lg*4;
      const int cc = tn + wn + ni*16 + la;
      if constexpr (OBF16) {
        u16* C = (u16*)Cv + (size_t)blockIdx.z * M * N;
#pragma unroll
        for (int r = 0; r < 4; ++r)
          C[(size_t)(r0 + r)*N + cc] = f2bf(acc[mi][ni][r]);
      } else {
        float* C = (float*)Cv + (size_t)blockIdx.z * M * N;
#pragma unroll
        for (int r = 0; r < 4; ++r)
          C[(size_t)(r0 + r)*N + cc] = acc[mi][ni][r];
      }
    }
}

// ---------- kernel: expand base+LoRA, RoPE, write Q/K/V (bf16 partials) ----------
__global__ __launch_bounds__(256)
void k_expand(const u16* __restrict__ proj, const float* __restrict__ wqb,
              const float* __restrict__ wkb, const float* __restrict__ wvb,
              const float* __restrict__ freq, u16* __restrict__ Q,
              u16* __restrict__ Kb, u16* __restrict__ Vt) {
  __shared__ float prs[256];
  const int s = blockIdx.x;
  {
    const int c = threadIdx.x;
    const u16* p0 = proj + s*256;
    float acc = 0.f;
#pragma unroll
    for (int k = 0; k < 8; ++k) acc += bf2f(p0[c + k*524288]);
    prs[c] = acc;
  }
  __syncthreads();
  const int d = threadIdx.x & 63;
  const int w = threadIdx.x >> 6;
  const float cs = freq[s*64 + (d & 62)];
  const float sn = freq[s*64 + (d & 62) + 1];
#pragma unroll
  for (int pass = 0; pass < 6; ++pass) {
    const int slot = pass*4 + w;
    int bcol, tb; const float* wb;
    if (slot < 16)      { bcol = 0;   tb = 192; wb = wqb + (slot*64 + d)*8; }
    else if (slot < 20) { bcol = 64;  tb = 200; wb = wkb + ((slot-16)*64 + d)*8; }
    else                { bcol = 128; tb = 208; wb = wvb + ((slot-20)*64 + d)*8; }
    float val = prs[bcol + d];
#pragma unroll
    for (int r = 0; r < 8; ++r) val += prs[tb + r] * wb[r];
    if (slot < 20) {  // RoPE
      float partner = __shfl_xor(val, 1);
      val = (d & 1) ? (partner*sn + val*cs) : (val*cs - partner*sn);
    }
    u16 o = f2bf(val);
    if (slot < 16)      Q [((size_t)slot*2048 + s)*64 + d] = o;
    else if (slot < 20) Kb[((size_t)(slot-16)*2048 + s)*64 + d] = o;
    else                Vt[(size_t)(slot-20)*131072 + (size_t)d*2048 + s] = o;
  }
}

// ---------- kernel: causal flash attention (v14: v10 + counted vmcnt) ----------
__global__ __launch_bounds__(256, 4)
void k_attn(const u16* __restrict__ Q, const u16* __restrict__ Kb,
            const u16* __restrict__ Vt, u16* __restrict__ O) {
  __shared__ __align__(16) char smem[33792];  // 4x8KB wave staging | comb | scr
  const int w = threadIdx.x >> 6, l = threadIdx.x & 63;
  const int bid = blockIdx.x;
  const int h = bid & 15, kh = h >> 2;
  const int z = bid >> 4;
  const int a = z & 15, b = z >> 4;            // stride-256 co-residents share a
  const int qs = (b << 4) | ((b & 1) ? (15 - a) : a);  // per-CU work pairing
  const int q0 = qs*32;
  const int lq = l & 31, hh = l >> 5;
  const int qg = q0 + lq;

  u16* kbuf = (u16*)(smem + w*8192);           // [32 t][64 d]  4KB, swizzled
  u16* vbuf = (u16*)(smem + w*8192 + 4096);    // [32 r][d=r|r+32][32 t] 4KB

  const u16* Qh = Q  + (size_t)h *131072;
  const u16* Kh = Kb + (size_t)kh*131072;
  const u16* Vh = Vt + (size_t)kh*131072;

  short8 bq[4];
#pragma unroll
  for (int ks = 0; ks < 4; ++ks)
    bq[ks] = *(const short8*)&Qh[qg*64 + ks*16 + hh*8];

  f32x16 acc0, acc1;                // O^T [d][q] partial (d 0..31 / 32..63)
#pragma unroll
  for (int r = 0; r < 16; ++r) { acc0[r] = 0.f; acc1[r] = 0.f; }
  float lsum = 0.f;
  const float SM = 20.f;            // static softmax offset (log2 domain)

  const int nt = qs + 1;            // 32-row t-tiles

#define STAGE_K(T0)                                                       \
  {                                                                       \
    const int t0_ = (T0);                                                 \
    _Pragma("unroll")                                                     \
    for (int j = 0; j < 4; ++j) {                                         \
      const int c = j*64 + l;                                             \
      const int row = c >> 3, e = (c & 7) ^ (row & 7);                    \
      async_ld16(Kh + (size_t)(t0_ + row)*64 + e*8, kbuf + j*512);        \
    }                                                                     \
  }
#define STAGE_V(T0)                                                       \
  {                                                                       \
    const int t0_ = (T0);                                                 \
    _Pragma("unroll")                                                     \
    for (int j = 0; j < 4; ++j) {                                         \
      const int c = j*64 + l;                                             \
      const int row = c >> 3, e = (c & 7) ^ (row & 7);                    \
      const int dd = row + (e >> 2)*32;                                   \
      async_ld16(Vh + (size_t)dd*2048 + t0_ + (e & 3)*8, vbuf + j*512);   \
    }                                                                     \
  }

  if (w < nt) { STAGE_K(w*32); STAGE_V(w*32); }

  for (int tt = w; tt < nt; tt += 4) {
    // outstanding here: K(tt) x4 (oldest), V(tt) x4 -> wait K only
    asm volatile("s_waitcnt vmcnt(4)" ::: "memory");
    __builtin_amdgcn_sched_barrier(0);
    // ---- K frags -> regs; fence; restage K (overlaps QK^T) ----
    short8 ak[4];
#pragma unroll
    for (int ks = 0; ks < 4; ++ks)
      ak[ks] = lds_rd(kbuf, lq, ks*32 + hh*16);
    asm volatile("s_waitcnt lgkmcnt(0)" ::: "memory");
    __builtin_amdgcn_sched_barrier(0);
    const bool restage = (tt + 4 < nt);
    if (restage) STAGE_K((tt + 4)*32);

    // ---- QK^T swapped: S^T[t32][q32] = mfma(K rows, Q rows) ----
    f32x16 s;
#pragma unroll
    for (int r = 0; r < 16; ++r) s[r] = 0.f;
    __builtin_amdgcn_s_setprio(1);
#pragma unroll
    for (int ks = 0; ks < 4; ++ks)
      s = mfma32(ak[ks], bq[ks], s);
    __builtin_amdgcn_s_setprio(0);

    // ---- causal mask (last tile only) ----
    const int t0 = tt*32;
    if (t0 + 31 > q0) {
#pragma unroll
      for (int r = 0; r < 16; ++r) {
        const int tl = (r & 3) + ((r >> 2) << 3) + (hh << 2);
        if (t0 + tl > qg) s[r] = -1e30f;
      }
    }

    // ---- wait V(tt) (oldest remaining); K(tt+4) stays in flight ----
    if (restage) { asm volatile("s_waitcnt vmcnt(4)" ::: "memory"); }
    else         { asm volatile("s_waitcnt vmcnt(0)" ::: "memory"); }
    __builtin_amdgcn_sched_barrier(0);
    short8 av[2][2];
#pragma unroll
    for (int dh = 0; dh < 2; ++dh)
#pragma unroll
      for (int k2 = 0; k2 < 2; ++k2)
        av[dh][k2] = lds_rd(vbuf, lq, (dh*4 + k2*2 + hh)*16);

    // ---- P = exp2(S - SM), packed bf16x2 ----
    unsigned cw[4][2];
    float psum = 0.f;
#pragma unroll
    for (int rq = 0; rq < 4; ++rq) {
      float a0 = exp2f(s[4*rq+0] - SM), a1 = exp2f(s[4*rq+1] - SM);
      float a2 = exp2f(s[4*rq+2] - SM), a3 = exp2f(s[4*rq+3] - SM);
      psum += (a0 + a1) + (a2 + a3);
      cw[rq][0] = cvtpk(a0, a1); cw[rq][1] = cvtpk(a2, a3);
    }
    lsum += psum;

    // ---- fence V reads; restage V (overlaps exchange + PV) ----
    asm volatile("s_waitcnt lgkmcnt(0)" ::: "memory");
    __builtin_amdgcn_sched_barrier(0);
    if (restage) STAGE_V((tt + 4)*32);

    // ---- cross-half exchange -> PV B-fragments ----
    unsigned y00 = __shfl_xor(hh ? cw[0][0] : cw[1][0], 32);
    unsigned y01 = __shfl_xor(hh ? cw[0][1] : cw[1][1], 32);
    unsigned y10 = __shfl_xor(hh ? cw[2][0] : cw[3][0], 32);
    unsigned y11 = __shfl_xor(hh ? cw[2][1] : cw[3][1], 32);
    short8 p0 = hh ? mkfrag(y00, y01, cw[1][0], cw[1][1])
                   : mkfrag(cw[0][0], cw[0][1], y00, y01);
    short8 p1 = hh ? mkfrag(y10, y11, cw[3][0], cw[3][1])
                   : mkfrag(cw[2][0], cw[2][1], y10, y11);

    // ---- PV: O^T[d][q] += mfma(V^T rows (k=t), P rows (k=t)) ----
    __builtin_amdgcn_s_setprio(1);
    acc0 = mfma32(av[0][0], p0, acc0);
    acc1 = mfma32(av[1][0], p0, acc1);
    acc0 = mfma32(av[0][1], p1, acc0);
    acc1 = mfma32(av[1][1], p1, acc1);
    __builtin_amdgcn_s_setprio(0);
  }
#undef STAGE_K
#undef STAGE_V

  // ---- combine: waves 1-3 publish partials; wave 0 sums + epilogue ----
  __syncthreads();                      // staging LDS now dead -> reuse
  float* comb = (float*)smem;           // [3][64][33] f32 = 25.3KB
  u16* scr = (u16*)(smem + 26624);      // 4KB transpose scratch
  if (w > 0) {
    float* cb = comb + ((w-1)*64 + l)*33;
#pragma unroll
    for (int r = 0; r < 16; ++r) { cb[r] = acc0[r]; cb[16+r] = acc1[r]; }
    cb[32] = lsum;
  }
  __syncthreads();
  if (w == 0) {
#pragma unroll
    for (int j = 0; j < 3; ++j) {
      const float* cb = comb + (j*64 + l)*33;
#pragma unroll
      for (int r = 0; r < 16; ++r) { acc0[r] += cb[r]; acc1[r] += cb[16+r]; }
      lsum += cb[32];
    }
    lsum += __shfl_xor(lsum, 32);
    const float inv = 1.f / lsum;
#pragma unroll
    for (int dt = 0; dt < 2; ++dt)
#pragma unroll
      for (int rq = 0; rq < 4; ++rq) {
        float v0 = (dt ? acc1[4*rq+0] : acc0[4*rq+0]) * inv;
        float v1 = (dt ? acc1[4*rq+1] : acc0[4*rq+1]) * inv;
        float v2 = (dt ? acc1[4*rq+2] : acc0[4*rq+2]) * inv;
        float v3 = (dt ? acc1[4*rq+3] : acc0[4*rq+3]) * inv;
        const int dby = dt*64 + rq*16 + hh*8;
        const int by = lq*128 + (dby ^ ((lq & 7) << 4));
        *(unsigned*)((char*)scr + by)     = cvtpk(v0, v1);
        *(unsigned*)((char*)scr + by + 4) = cvtpk(v2, v3);
      }
#pragma unroll
    for (int qq = 0; qq < 4; ++qq) {
      const int qrow = qq*8 + (l >> 3);
      const int by = qrow*128 + (((l & 7) << 4) ^ ((qrow & 7) << 4));
      short8 v = *(const short8*)((const char*)scr + by);
      *(short8*)&O[(size_t)(q0 + qrow)*1024 + h*64 + (l & 7)*8] = v;
    }
  }
}

// ---------- launch ----------
extern "C" void kernel_launch(void* const* d_in, const int* in_sizes, int n_in,
                              void* d_out, int out_size, void* d_ws, size_t ws_size,
                              hipStream_t stream) {
  const float* x    = (const float*)d_in[0];
  const float* freq = (const float*)d_in[1];
  const float* wq   = (const float*)d_in[2];
  const float* wqa  = (const float*)d_in[3];
  const float* wqb  = (const float*)d_in[4];
  const float* wk   = (const float*)d_in[5];
  const float* wka  = (const float*)d_in[6];
  const float* wkb  = (const float*)d_in[7];
  const float* wv   = (const float*)d_in[8];
  const float* wva  = (const float*)d_in[9];
  const float* wvb  = (const float*)d_in[10];
  const float* wo   = (const float*)d_in[11];
  const float* wos  = (const float*)d_in[12];

  char* ws = (char*)d_ws;
  u16*  x_bf = (u16*)ws;
  u16*  Qb   = (u16*)ws;                  // reuses x_bf region (stream-ordered)
  u16*  Kbuf = (u16*)(ws + (4u<<20));
  u16*  Vtb  = (u16*)(ws + (5u<<20));
  u16*  W1   = (u16*)(ws + (8u<<20));
  u16*  Weff = (u16*)(ws + (9u<<20));
  u16*  proj = (u16*)(ws + (13u<<20));    // 8 x [2048][256] bf16 = 8MB
  u16*  Obf  = (u16*)(ws + (13u<<20));    // reuses proj region (after expand)

  k_prep    <<<3328, 256, 0, stream>>>(x, wq, wk, wv, wqa, wka, wva, wo, wos,
                                       x_bf, W1, Weff);
  k_gemm_bt<128,64,true><<<dim3(4,16,8), 512, 0, stream>>>(x_bf, W1, proj,
                                                           2048, 256, 2048, 256);
  k_expand  <<<dim3(2048), 256, 0, stream>>>(proj, wqb, wkb, wvb, freq, Qb, Kbuf, Vtb);
  k_attn    <<<dim3(1024), 256, 0, stream>>>(Qb, Kbuf, Vtb, Obf);
  k_gemm_bt<64,128,false><<<dim3(16,32,1), 512, 0, stream>>>(Obf, Weff, (float*)d_out,
                                                             2048, 2048, 1024, 1024);
}